// Round 3
// baseline (602.251 us; speedup 1.0000x reference)
//
#include <hip/hip_runtime.h>

// GAT layer, fused, zero-workspace, f32 I/O.
// B=8, N=1024, F_IN=25, H=8, D=16
// out0 = relu(h_prime) (8,1024,128) f32 ; out1 = alpha (8,8,1024,1024) f32
#define NEG_INF_F (-9.0e15f)
#define L2E 1.44269504f

typedef short short8_t __attribute__((ext_vector_type(8)));
typedef float fltx4    __attribute__((ext_vector_type(4)));
typedef int   intx4    __attribute__((ext_vector_type(4)));
typedef unsigned int uint32;

__device__ __forceinline__ unsigned short f2bf(float f) {
    uint32 u = __float_as_uint(f);
    u += 0x7FFFu + ((u >> 16) & 1u);   // RNE
    return (unsigned short)(u >> 16);
}

// One block per (bh, chunk): bh = b*8+h in [0,64), chunk in [0,16) -> 64 rows.
// 4 waves; each wave owns 16 rows for softmax + PV.
__global__ __launch_bounds__(256) void gat_fused(
    const float* __restrict__ x,     // (8,1024,25) f32
    const int*   __restrict__ adj,   // (8,1024,1024) int32
    const float* __restrict__ W,     // (8,25,16) f32
    const float* __restrict__ a,     // (8,32) f32
    float* __restrict__ out0,        // (8,1024,128) f32
    float* __restrict__ out1)        // (8,8,1024,1024) f32
{
    // whb: Wh (bf16) in MFMA B-fragment layout:
    //   whb[((k>>5)*64 + ((k>>3)&3)*16 + d)*8 + (k&7)] = Wh[k][d]
    __shared__ __align__(16) unsigned short whb[32 * 64 * 8];  // 32 KB
    __shared__ __align__(16) float ej_lds[1024];               // 4 KB
    __shared__ float ei_lds[64];
    __shared__ float wa[64];   // [0:25] W@a_src, [32:57] W@a_dst

    const int bh    = blockIdx.x >> 4;
    const int chunk = blockIdx.x & 15;
    const int b     = bh >> 3;
    const int h     = bh & 7;
    const int tid   = threadIdx.x;
    const int wave  = tid >> 6;
    const int lane  = tid & 63;
    const int mrow  = lane & 15;
    const int quad  = lane >> 4;

    const float* Wp = W + h * 25 * 16;
    const float* ap = a + h * 32;
    const float* xb = x + (size_t)b * 1024 * 25;

    // ---- wa = W @ a_src / a_dst (tiny, exact f32) ----
    if (tid < 50) {
        int f = tid % 25, which = tid / 25;   // 0 = src, 1 = dst
        float s = 0.f;
        #pragma unroll
        for (int d = 0; d < 16; ++d)
            s += Wp[f * 16 + d] * ap[which * 16 + d];
        wa[which * 32 + f] = s;
    }
    __syncthreads();

    // ---- per thread, 4 node rows: ei/ej (f32) + Wh row (f32 -> bf16 LDS) ----
    for (int s = 0; s < 4; ++s) {
        int n = tid + (s << 8);
        const float* xr = xb + n * 25;
        float xf[25];
        #pragma unroll
        for (int f = 0; f < 25; ++f) xf[f] = xr[f];

        float vi = 0.f, vj = 0.f;
        #pragma unroll
        for (int f = 0; f < 25; ++f) {
            vi += xf[f] * wa[f];
            vj += xf[f] * wa[32 + f];
        }
        ej_lds[n] = vj;
        if ((n >> 6) == chunk) ei_lds[n & 63] = vi;

        int base = (((n >> 5) * 64 + ((n >> 3) & 3) * 16) << 3) + (n & 7);
        #pragma unroll
        for (int d = 0; d < 16; ++d) {
            float s2 = 0.f;
            #pragma unroll
            for (int f = 0; f < 25; ++f) s2 += xf[f] * Wp[f * 16 + d];
            whb[base + d * 8] = f2bf(s2);
        }
    }
    __syncthreads();

    // ---- Phase A: softmax rows i0..i0+15 (no max-subtract; |e|<=~12) ----
    const int i0 = chunk * 64 + wave * 16;
    float* abase = out1 + (size_t)bh * 1024 * 1024;
    const fltx4* ej4 = (const fltx4*)ej_lds;

    for (int r = 0; r < 16; ++r) {
        int i = i0 + r;
        float s_ei = ei_lds[wave * 16 + r];
        const intx4* adj4 = (const intx4*)(adj + ((size_t)b * 1024 + i) * 1024);

        float p[16];
        float sum = 0.f;
        #pragma unroll
        for (int j0 = 0; j0 < 4; ++j0) {
            int idx = j0 * 64 + lane;                    // j = idx*4 .. +3
            intx4 av = __builtin_nontemporal_load(&adj4[idx]);
            fltx4 ev = ej4[idx];
            float p0 = av.x ? exp2f((s_ei + ev.x) * L2E) : 0.f;
            float p1 = av.y ? exp2f((s_ei + ev.y) * L2E) : 0.f;
            float p2 = av.z ? exp2f((s_ei + ev.z) * L2E) : 0.f;
            float p3 = av.w ? exp2f((s_ei + ev.w) * L2E) : 0.f;
            p[j0 * 4 + 0] = p0; p[j0 * 4 + 1] = p1;
            p[j0 * 4 + 2] = p2; p[j0 * 4 + 3] = p3;
            sum += (p0 + p1) + (p2 + p3);
        }
        #pragma unroll
        for (int off = 32; off; off >>= 1) sum += __shfl_xor(sum, off);

        float rinv;
        if (sum > 0.f) {
            rinv = 1.0f / sum;
        } else {
            // fully-masked row: reference softmax of constant -9e15 -> uniform
            rinv = 1.0f;
            #pragma unroll
            for (int k = 0; k < 16; ++k) p[k] = 1.0f / 1024.0f;
        }

        float* arow = abase + (size_t)i * 1024;
        #pragma unroll
        for (int j0 = 0; j0 < 4; ++j0) {
            fltx4 st;
            st.x = p[j0 * 4 + 0] * rinv;
            st.y = p[j0 * 4 + 1] * rinv;
            st.z = p[j0 * 4 + 2] * rinv;
            st.w = p[j0 * 4 + 3] * rinv;
            *(fltx4*)(arow + (j0 * 64 + lane) * 4) = st;
        }
    }

    __threadfence();   // drain alpha stores; invalidate L1 before re-read

    // ---- Phase B: h_prime(16x16) = alpha(16x1024) @ Wh(1024x16) via MFMA ----
    const float* aptr = abase + (size_t)(i0 + mrow) * 1024 + quad * 8;
    fltx4 acc = {0.f, 0.f, 0.f, 0.f};
    for (int ks = 0; ks < 32; ++ks) {
        fltx4 a0 = *(const fltx4*)(aptr + ks * 32);
        fltx4 a1 = *(const fltx4*)(aptr + ks * 32 + 4);
        short8_t afr;
        #pragma unroll
        for (int q = 0; q < 4; ++q) {
            afr[q]     = (short)f2bf(a0[q]);
            afr[4 + q] = (short)f2bf(a1[q]);
        }
        short8_t bfr = *(const short8_t*)&whb[((ks * 64 + lane) << 3)];
        acc = __builtin_amdgcn_mfma_f32_16x16x32_bf16(afr, bfr, acc, 0, 0, 0);
    }

    // C layout: col = mrow (=d), row = quad*4 + reg
    #pragma unroll
    for (int r = 0; r < 4; ++r) {
        int i = i0 + quad * 4 + r;
        float v = acc[r] > 0.f ? acc[r] : 0.f;
        out0[((size_t)(b * 1024 + i)) * 128 + h * 16 + mrow] = v;
    }
}

extern "C" void kernel_launch(void* const* d_in, const int* in_sizes, int n_in,
                              void* d_out, int out_size, void* d_ws, size_t ws_size,
                              hipStream_t stream) {
    const float* x   = (const float*)d_in[0];  // node_feats f32
    const int*   adj = (const int*)d_in[1];    // adj int32
    const float* W   = (const float*)d_in[2];  // W f32
    const float* a   = (const float*)d_in[3];  // a f32

    float* out0 = (float*)d_out;                        // (8,1024,128)
    float* out1 = out0 + (size_t)8 * 1024 * 128;        // (8,8,1024,1024)

    gat_fused<<<1024, 256, 0, stream>>>(x, adj, W, a, out0, out1);
}

// Round 5
// 561.955 us; speedup vs baseline: 1.0717x; 1.0717x over previous
//
#include <hip/hip_runtime.h>

// GAT layer: B=8, N=1024, F_IN=25, H=8, D=16, f32 I/O.
// out0 = relu(h_prime) (8,1024,128) f32 ; out1 = alpha (8,8,1024,1024) f32
#define NEG_INF_F (-9.0e15f)
#define L2E 1.44269504f

typedef short short8_t __attribute__((ext_vector_type(8)));
typedef float fltx4    __attribute__((ext_vector_type(4)));
typedef int   intx4    __attribute__((ext_vector_type(4)));
typedef unsigned int uint32;

__device__ __forceinline__ unsigned short f2bf(float f) {
    uint32 u = __float_as_uint(f);
    u += 0x7FFFu + ((u >> 16) & 1u);   // RNE
    return (unsigned short)(u >> 16);
}

// ---------------------------------------------------------------------------
// prep_once: per (bh, n): Wh row (f32 -> bf16, MFMA B-frag layout in ws),
// ei = Wh.a_src, ej = Wh.a_dst (f32 in ws). Runs ONCE per (b,h) row.
//   whb[ bh*16384 + ((n>>5)*64 + ((n>>3)&3)*16 + d)*8 + (n&7) ] = Wh[n][d]
// ---------------------------------------------------------------------------
__global__ __launch_bounds__(256) void prep_once(
    const float* __restrict__ x,      // (8,1024,25)
    const float* __restrict__ W,      // (8,25,16)
    const float* __restrict__ a,      // (8,32)
    float* __restrict__ ei_ws,        // (64,1024)
    float* __restrict__ ej_ws,        // (64,1024)
    unsigned short* __restrict__ whb) // (64,32,64,8) bf16
{
    int t  = blockIdx.x * 256 + threadIdx.x;   // 65536
    int bh = t >> 10, n = t & 1023;
    int b  = bh >> 3, h = bh & 7;

    const float* xr = x + ((size_t)(b * 1024 + n)) * 25;
    const float* Wp = W + h * 400;
    const float* ap = a + h * 32;

    float xf[25];
    #pragma unroll
    for (int f = 0; f < 25; ++f) xf[f] = xr[f];

    int base = ((bh * 32 + (n >> 5)) * 64 + ((n >> 3) & 3) * 16) * 8 + (n & 7);
    float vi = 0.f, vj = 0.f;
    #pragma unroll
    for (int d = 0; d < 16; ++d) {
        float s = 0.f;
        #pragma unroll
        for (int f = 0; f < 25; ++f) s += xf[f] * Wp[f * 16 + d];
        vi += s * ap[d];
        vj += s * ap[16 + d];
        whb[base + d * 8] = f2bf(s);
    }
    ei_ws[t] = vi;
    ej_ws[t] = vj;
}

// ---------------------------------------------------------------------------
// gat_main: one block per (b, chunk, h), h fastest (adj L2 reuse across heads).
// 4 waves x 16 rows. Zero LDS. ej held in 16 registers per lane.
// ---------------------------------------------------------------------------
__global__ __launch_bounds__(256) void gat_main(
    const int*   __restrict__ adj,    // (8,1024,1024)
    const float* __restrict__ ei_ws,
    const float* __restrict__ ej_ws,
    const unsigned short* __restrict__ whb,
    float* __restrict__ out0,         // (8,1024,128)
    float* __restrict__ out1)         // (8,8,1024,1024)
{
    const int blk   = blockIdx.x;
    const int h     = blk & 7;
    const int chunk = (blk >> 3) & 15;
    const int b     = blk >> 7;
    const int bh    = b * 8 + h;
    const int wave  = threadIdx.x >> 6;
    const int lane  = threadIdx.x & 63;
    const int mrow  = lane & 15;
    const int quad  = lane >> 4;
    const int i0    = chunk * 64 + wave * 16;

    // ej for this lane's 16 columns -> registers, reused for all 16 rows
    const fltx4* ej4 = (const fltx4*)(ej_ws + bh * 1024);
    fltx4 ejr[4];
    #pragma unroll
    for (int j0 = 0; j0 < 4; ++j0) ejr[j0] = ej4[j0 * 64 + lane];

    const float* eib = ei_ws + bh * 1024;
    float* abase = out1 + (size_t)bh * 1024 * 1024;

    // ---- Phase A: softmax rows i0..i0+15 ----
    for (int r = 0; r < 16; ++r) {
        int i = i0 + r;
        float s_ei = eib[i];
        const intx4* adj4 = (const intx4*)(adj + ((size_t)b * 1024 + i) * 1024);

        float p[16];
        float sum = 0.f;
        #pragma unroll
        for (int j0 = 0; j0 < 4; ++j0) {
            intx4 av = adj4[j0 * 64 + lane];
            fltx4 ev = ejr[j0];
            float p0 = av.x ? exp2f((s_ei + ev.x) * L2E) : 0.f;
            float p1 = av.y ? exp2f((s_ei + ev.y) * L2E) : 0.f;
            float p2 = av.z ? exp2f((s_ei + ev.z) * L2E) : 0.f;
            float p3 = av.w ? exp2f((s_ei + ev.w) * L2E) : 0.f;
            p[j0 * 4 + 0] = p0; p[j0 * 4 + 1] = p1;
            p[j0 * 4 + 2] = p2; p[j0 * 4 + 3] = p3;
            sum += (p0 + p1) + (p2 + p3);
        }
        #pragma unroll
        for (int off = 32; off; off >>= 1) sum += __shfl_xor(sum, off);

        float rinv;
        if (sum > 0.f) {
            rinv = 1.0f / sum;
        } else {
            rinv = 1.0f;   // fully-masked row -> uniform 1/1024
            #pragma unroll
            for (int k = 0; k < 16; ++k) p[k] = 1.0f / 1024.0f;
        }

        float* arow = abase + (size_t)i * 1024;
        #pragma unroll
        for (int j0 = 0; j0 < 4; ++j0) {
            fltx4 st;
            st.x = p[j0 * 4 + 0] * rinv;
            st.y = p[j0 * 4 + 1] * rinv;
            st.z = p[j0 * 4 + 2] * rinv;
            st.w = p[j0 * 4 + 3] * rinv;
            *(fltx4*)(arow + (j0 * 64 + lane) * 4) = st;
        }
    }

    __threadfence();

    // ---- Phase B: h_prime(16x16) = alpha(16x1024) @ Wh(1024x16) ----
    const float* aptr = abase + (size_t)(i0 + mrow) * 1024 + quad * 8;
    const unsigned short* bbase = whb + (size_t)bh * 16384;
    fltx4 acc = {0.f, 0.f, 0.f, 0.f};
    #pragma unroll 4
    for (int ks = 0; ks < 32; ++ks) {
        fltx4 a0 = *(const fltx4*)(aptr + ks * 32);
        fltx4 a1 = *(const fltx4*)(aptr + ks * 32 + 4);
        short8_t afr;
        #pragma unroll
        for (int q = 0; q < 4; ++q) {
            afr[q]     = (short)f2bf(a0[q]);
            afr[4 + q] = (short)f2bf(a1[q]);
        }
        short8_t bfr = *(const short8_t*)(bbase + ((ks * 64 + lane) << 3));
        acc = __builtin_amdgcn_mfma_f32_16x16x32_bf16(afr, bfr, acc, 0, 0, 0);
    }

    // C layout: col = mrow (=d), row = quad*4 + reg
    #pragma unroll
    for (int r = 0; r < 4; ++r) {
        int i = i0 + quad * 4 + r;
        float v = acc[r] > 0.f ? acc[r] : 0.f;
        out0[((size_t)(b * 1024 + i)) * 128 + h * 16 + mrow] = v;
    }
}

// ---------------------------------------------------------------------------
// Fallback: round-3 fused kernel (known correct), used if ws_size too small.
// ---------------------------------------------------------------------------
__global__ __launch_bounds__(256) void gat_fused(
    const float* __restrict__ x, const int* __restrict__ adj,
    const float* __restrict__ W, const float* __restrict__ a,
    float* __restrict__ out0, float* __restrict__ out1)
{
    __shared__ __align__(16) unsigned short whb[32 * 64 * 8];
    __shared__ __align__(16) float ej_lds[1024];
    __shared__ float ei_lds[64];
    __shared__ float wa[64];

    const int bh    = blockIdx.x >> 4;
    const int chunk = blockIdx.x & 15;
    const int b     = bh >> 3;
    const int h     = bh & 7;
    const int tid   = threadIdx.x;
    const int wave  = tid >> 6;
    const int lane  = tid & 63;
    const int mrow  = lane & 15;
    const int quad  = lane >> 4;

    const float* Wp = W + h * 400;
    const float* ap = a + h * 32;
    const float* xb = x + (size_t)b * 1024 * 25;

    if (tid < 50) {
        int f = tid % 25, which = tid / 25;
        float s = 0.f;
        #pragma unroll
        for (int d = 0; d < 16; ++d) s += Wp[f * 16 + d] * ap[which * 16 + d];
        wa[which * 32 + f] = s;
    }
    __syncthreads();

    for (int s = 0; s < 4; ++s) {
        int n = tid + (s << 8);
        const float* xr = xb + n * 25;
        float xf[25];
        #pragma unroll
        for (int f = 0; f < 25; ++f) xf[f] = xr[f];
        float vi = 0.f, vj = 0.f;
        #pragma unroll
        for (int f = 0; f < 25; ++f) { vi += xf[f] * wa[f]; vj += xf[f] * wa[32 + f]; }
        ej_lds[n] = vj;
        if ((n >> 6) == chunk) ei_lds[n & 63] = vi;
        int base = (((n >> 5) * 64 + ((n >> 3) & 3) * 16) << 3) + (n & 7);
        #pragma unroll
        for (int d = 0; d < 16; ++d) {
            float s2 = 0.f;
            #pragma unroll
            for (int f = 0; f < 25; ++f) s2 += xf[f] * Wp[f * 16 + d];
            whb[base + d * 8] = f2bf(s2);
        }
    }
    __syncthreads();

    const int i0 = chunk * 64 + wave * 16;
    float* abase = out1 + (size_t)bh * 1024 * 1024;
    const fltx4* ej4 = (const fltx4*)ej_lds;

    for (int r = 0; r < 16; ++r) {
        int i = i0 + r;
        float s_ei = ei_lds[wave * 16 + r];
        const intx4* adj4 = (const intx4*)(adj + ((size_t)b * 1024 + i) * 1024);
        float p[16];
        float sum = 0.f;
        #pragma unroll
        for (int j0 = 0; j0 < 4; ++j0) {
            intx4 av = adj4[j0 * 64 + lane];
            fltx4 ev = ej4[j0 * 64 + lane];
            float p0 = av.x ? exp2f((s_ei + ev.x) * L2E) : 0.f;
            float p1 = av.y ? exp2f((s_ei + ev.y) * L2E) : 0.f;
            float p2 = av.z ? exp2f((s_ei + ev.z) * L2E) : 0.f;
            float p3 = av.w ? exp2f((s_ei + ev.w) * L2E) : 0.f;
            p[j0 * 4 + 0] = p0; p[j0 * 4 + 1] = p1;
            p[j0 * 4 + 2] = p2; p[j0 * 4 + 3] = p3;
            sum += (p0 + p1) + (p2 + p3);
        }
        #pragma unroll
        for (int off = 32; off; off >>= 1) sum += __shfl_xor(sum, off);
        float rinv;
        if (sum > 0.f) {
            rinv = 1.0f / sum;
        } else {
            rinv = 1.0f;
            #pragma unroll
            for (int k = 0; k < 16; ++k) p[k] = 1.0f / 1024.0f;
        }
        float* arow = abase + (size_t)i * 1024;
        #pragma unroll
        for (int j0 = 0; j0 < 4; ++j0) {
            fltx4 st;
            st.x = p[j0 * 4 + 0] * rinv; st.y = p[j0 * 4 + 1] * rinv;
            st.z = p[j0 * 4 + 2] * rinv; st.w = p[j0 * 4 + 3] * rinv;
            *(fltx4*)(arow + (j0 * 64 + lane) * 4) = st;
        }
    }

    __threadfence();

    const float* aptr = abase + (size_t)(i0 + mrow) * 1024 + quad * 8;
    fltx4 acc = {0.f, 0.f, 0.f, 0.f};
    for (int ks = 0; ks < 32; ++ks) {
        fltx4 a0 = *(const fltx4*)(aptr + ks * 32);
        fltx4 a1 = *(const fltx4*)(aptr + ks * 32 + 4);
        short8_t afr;
        #pragma unroll
        for (int q = 0; q < 4; ++q) {
            afr[q]     = (short)f2bf(a0[q]);
            afr[4 + q] = (short)f2bf(a1[q]);
        }
        short8_t bfr = *(const short8_t*)&whb[((ks * 64 + lane) << 3)];
        acc = __builtin_amdgcn_mfma_f32_16x16x32_bf16(afr, bfr, acc, 0, 0, 0);
    }
    #pragma unroll
    for (int r = 0; r < 4; ++r) {
        int i = i0 + quad * 4 + r;
        float v = acc[r] > 0.f ? acc[r] : 0.f;
        out0[((size_t)(b * 1024 + i)) * 128 + h * 16 + mrow] = v;
    }
}

extern "C" void kernel_launch(void* const* d_in, const int* in_sizes, int n_in,
                              void* d_out, int out_size, void* d_ws, size_t ws_size,
                              hipStream_t stream) {
    const float* x   = (const float*)d_in[0];
    const int*   adj = (const int*)d_in[1];
    const float* W   = (const float*)d_in[2];
    const float* a   = (const float*)d_in[3];

    float* out0 = (float*)d_out;                    // (8,1024,128)
    float* out1 = out0 + (size_t)8 * 1024 * 128;    // (8,8,1024,1024)

    const size_t WHB_BYTES = (size_t)64 * 16384 * 2;      // 2 MB
    const size_t EI_BYTES  = (size_t)64 * 1024 * 4;       // 256 KB
    const size_t NEED      = WHB_BYTES + 2 * EI_BYTES;    // 2.5 MB

    if (ws_size >= NEED) {
        unsigned short* whb = (unsigned short*)d_ws;
        float* ei_ws = (float*)((char*)d_ws + WHB_BYTES);
        float* ej_ws = ei_ws + 64 * 1024;
        prep_once<<<256, 256, 0, stream>>>(x, W, a, ei_ws, ej_ws, whb);
        gat_main<<<1024, 256, 0, stream>>>(adj, ei_ws, ej_ws, whb, out0, out1);
    } else {
        gat_fused<<<1024, 256, 0, stream>>>(x, adj, W, a, out0, out1);
    }
}